// Round 5
// baseline (287.186 us; speedup 1.0000x reference)
//
#include <hip/hip_runtime.h>
#include <hip/hip_bf16.h>
#include <stdint.h>
#include <stddef.h>

// Problem constants
#define BATCH   4096
#define INDIM   512
#define OUTDIM  512
#define NH      32
#define KKDIM   64                 // 2*NH k-values per input dim
#define INV2PI  0.15915494309189535f

// Pipelined register-trig: 128x128 tile, 4 waves of 32x128, acc[2][8] AGPR.
// Rounds 0/1/4 all pinned at ~190us with MfmaUtil~32 / VALUBusy~50 / LDS~43%:
// phase-locked [trig burst][MFMA burst] per barrier interval -- pipes never
// overlap. This round: trig(it+1) -> avB while MFMA(it) consumes avA
// (independent dataflow, scheduler interleaves -> VALU+MFMA+LDS concurrent).
// x read direct from global (L1-resident tile) to pay the avB register cost;
// LDS = B dbuf only (32KB). ~136 unified regs -> 3 blocks/CU.
#define BM       128
#define BN       128
#define THREADS  256
#define KSPLIT   8
#define DIMS_PER_WG (INDIM / KSPLIT)     // 64 input dims per workgroup
#define CHUNK_COLS  256
#define CHUNK_ELEMS (CHUNK_COLS * KKDIM) // 16384 bf16 = 32 KB per (cb2, dim) chunk

#define B_BYTES       16384                    // [128 col][64 kk] bf16, xor-swizzled
#define SMEM_BYTES    (2 * B_BYTES)            // 32768

typedef short  bhalf8  __attribute__((ext_vector_type(8)));  // 8 bf16 (4 VGPRs)
typedef float  vfloat4 __attribute__((ext_vector_type(4)));

union AFrag { uint4 u; bhalf8 h; };

__device__ __forceinline__ unsigned pack_bf16(float a, float b) {
    union { __hip_bfloat162 h2; unsigned u; } cv;
    cv.h2 = __float22bfloat162_rn(float2{a, b});   // cos in low half (kk even), sin in high
    return cv.u;
}

__device__ __forceinline__ void async_copy16(const void* gsrc, void* ldst) {
    __builtin_amdgcn_global_load_lds(
        (const __attribute__((address_space(1))) void*)(uintptr_t)gsrc,
        (__attribute__((address_space(3))) void*)(uint32_t)(uintptr_t)ldst,
        16, 0, 0);
}

// ---------------------------------------------------------------------------
// Prepass (proven since round 1): fourier_coeffs fp32 [512,32,2,512] -> bf16
// chunks [256 col][64 kk] with 16B-unit swizzle pc = (kk>>3) ^ (col&7) baked
// in. Main kernel stages 16KB col-halves. Both global sides coalesced.
// ---------------------------------------------------------------------------
__global__ __launch_bounds__(256) void fkan_prepass(const float* __restrict__ coeffs,
                                                    unsigned short* __restrict__ Bt) {
    __shared__ float lds[64][260];   // pad 260: conflict-free f32x4 writes + scalar reads
    const int t  = threadIdx.x;
    const int cb = blockIdx.x & 1;
    const int i  = blockIdx.x >> 1;
    const float* __restrict__ src = coeffs + (size_t)i * (KKDIM * OUTDIM) + cb * CHUNK_COLS;
    unsigned short* __restrict__ chunk = Bt + (size_t)(cb * INDIM + i) * CHUNK_ELEMS;
#pragma unroll
    for (int rd = 0; rd < 16; ++rd) {
        const int r  = rd * 4 + (t >> 6);       // each wave loads one kk-row, coalesced
        const int c4 = (t & 63) * 4;
        const float4 v = *(const float4*)(src + (size_t)r * OUTDIM + c4);
        *(float4*)&lds[r][c4] = v;
    }
    __syncthreads();
#pragma unroll
    for (int s = 0; s < 8; ++s) {
        const int unit = t + s * 256;          // 2048 16B-units per chunk
        const int col  = unit >> 3;
        const int pc   = unit & 7;             // physical 16B slot in this col's row
        const int kb   = (pc ^ (col & 7)) * 8; // logical kk base held in this slot
        uint4 o;
        o.x = pack_bf16(lds[kb + 0][col], lds[kb + 1][col]);
        o.y = pack_bf16(lds[kb + 2][col], lds[kb + 3][col]);
        o.z = pack_bf16(lds[kb + 4][col], lds[kb + 5][col]);
        o.w = pack_bf16(lds[kb + 6][col], lds[kb + 7][col]);
        ((uint4*)chunk)[unit] = o;             // lane-contiguous coalesced store
    }
}

// out[b,o] = bias[o]
__global__ __launch_bounds__(256) void fkan_bias_init(const float* __restrict__ bias,
                                                      float* __restrict__ out) {
    const int idx = blockIdx.x * 256 + threadIdx.x;       // 524288 float4s
    ((float4*)out)[idx] = ((const float4*)bias)[idx & 127];
}

// ---------------------------------------------------------------------------
// Main fused kernel helpers
// ---------------------------------------------------------------------------
__device__ __forceinline__ void stage_B(const char* __restrict__ chunk_half, char* smem,
                                        int parity, int t) {
    char* bdst = smem + parity * B_BYTES;
#pragma unroll
    for (int s = 0; s < 4; ++s) {
        const int unit = t + s * 256;          // 1024 16B-units per 16KB half-chunk
        async_copy16(chunk_half + unit * 16, bdst + unit * 16);  // linear DMA dest
    }
}

// cos/sin((k0f+j)*rv) j=0..3 -> *a0, and ((k1f+j)*rv) -> *a1, packed bf16
// pairs. Slot-identical to the proven LDS A-tile layout of rounds 0/1.
__device__ __forceinline__ void make_av(float rv, float k0f, float k1f,
                                        bhalf8* a0, bhalf8* a1) {
    const float cd = __builtin_amdgcn_cosf(rv);   // step e^{ix} (revolution domain)
    const float sd = __builtin_amdgcn_sinf(rv);
    AFrag A;
    float c = __builtin_amdgcn_cosf(k0f * rv);
    float s = __builtin_amdgcn_sinf(k0f * rv);
    A.u.x = pack_bf16(c, s);
    { const float nc = c*cd - s*sd, ns = s*cd + c*sd; c = nc; s = ns; }
    A.u.y = pack_bf16(c, s);
    { const float nc = c*cd - s*sd, ns = s*cd + c*sd; c = nc; s = ns; }
    A.u.z = pack_bf16(c, s);
    { const float nc = c*cd - s*sd, ns = s*cd + c*sd; c = nc; s = ns; }
    A.u.w = pack_bf16(c, s);
    *a0 = A.h;
    c = __builtin_amdgcn_cosf(k1f * rv);
    s = __builtin_amdgcn_sinf(k1f * rv);
    A.u.x = pack_bf16(c, s);
    { const float nc = c*cd - s*sd, ns = s*cd + c*sd; c = nc; s = ns; }
    A.u.y = pack_bf16(c, s);
    { const float nc = c*cd - s*sd, ns = s*cd + c*sd; c = nc; s = ns; }
    A.u.z = pack_bf16(c, s);
    { const float nc = c*cd - s*sd, ns = s*cd + c*sd; c = nc; s = ns; }
    A.u.w = pack_bf16(c, s);
    *a1 = A.h;
}

// One dim's MFMA block: 8 col-tiles x 2 k-slots, consuming frag set (A0,A1).
#define MFMA_BLOCK(Bb, A0, A1)                                                  \
    do {                                                                        \
        _Pragma("unroll")                                                       \
        for (int ct = 0; ct < 8; ++ct) {                                        \
            const int cbyte = (ct * 16 + fr) * 128;                             \
            const bhalf8 b0 = *(const bhalf8*)((Bb) + cbyte + off0);            \
            acc[0][ct] = __builtin_amdgcn_mfma_f32_16x16x32_bf16(               \
                (A0)[0], b0, acc[0][ct], 0, 0, 0);                              \
            acc[1][ct] = __builtin_amdgcn_mfma_f32_16x16x32_bf16(               \
                (A0)[1], b0, acc[1][ct], 0, 0, 0);                              \
            const bhalf8 b1 = *(const bhalf8*)((Bb) + cbyte + off1);            \
            acc[0][ct] = __builtin_amdgcn_mfma_f32_16x16x32_bf16(               \
                (A1)[0], b1, acc[0][ct], 0, 0, 0);                              \
            acc[1][ct] = __builtin_amdgcn_mfma_f32_16x16x32_bf16(               \
                (A1)[1], b1, acc[1][ct], 0, 0, 0);                              \
        }                                                                       \
    } while (0)

// ---------------------------------------------------------------------------
// Main kernel: grid 1024 (= 32 rowblocks x 4 colblocks x 8 ksplits), 256 thr.
// grp = blockIdx&31 = cb4*8 + kq -> XCD (= blockIdx%8) is kq: L2 working set
// 64 dims x 32KB B + x slice = ~3MB <= 4MB (proven: FETCH 26MB, round 4).
// Loop is 2x-unrolled with av double-buffer: trig(it+1)->avB is independent
// of MFMA(it) on avA, so the scheduler interleaves VALU trig with MFMA and
// the per-wave [VALU burst][MFMA burst] phase-lock of rounds 0-4 breaks.
// ---------------------------------------------------------------------------
__global__ __launch_bounds__(THREADS, 3) void fkan_main(const float* __restrict__ x,
                                                        const unsigned short* __restrict__ Bt,
                                                        float* __restrict__ out) {
    __shared__ char smem[SMEM_BYTES];
    const int t      = threadIdx.x;
    const int grp    = blockIdx.x & 31;
    const int member = blockIdx.x >> 5;
    const int kq      = grp & 7;          // ksplit -> XCD
    const int cb4     = grp >> 3;         // col block (128 cols)
    const int cb2     = cb4 >> 1;         // prepass chunk (256-col) index
    const int rowbase = member * BM;
    const int colbase = cb4 * BN;
    const int dimbase = kq * DIMS_PER_WG;

    const int lane = t & 63;
    const int w    = t >> 6;       // wave grid 4x1; wave tile 32x128 (rows w*32..)
    const int fr   = lane & 15;    // row/col within 16x16 tile
    const int fq   = lane >> 4;    // quad -> k-chunk of 8 kk (4 harmonics)
    const int fx   = lane & 7;     // xor swizzle key for B (== col&7, tiles 16-aligned)
    const int off0 = (fq ^ fx) * 16;         // ks=0 swizzled slot
    const int off1 = ((4 + fq) ^ fx) * 16;   // ks=1 swizzled slot

    const float k0f = (float)(fq * 4 + 1);    // ks=0 base harmonic
    const float k1f = (float)(fq * 4 + 17);   // ks=1 base harmonic

    // Direct per-lane x access (rows w*32 + {fr, 16+fr}); tile is L1-resident.
    const float* __restrict__ xp0 = x + (size_t)(rowbase + w * 32 + fr) * INDIM + dimbase;
    const float* __restrict__ xp1 = xp0 + (size_t)16 * INDIM;

    // 16KB col-half of the (cb2, dim) 32KB chunk; dims stride 32KB.
    const char* __restrict__ chunkbase =
        (const char*)(Bt + (size_t)(cb2 * INDIM + dimbase) * CHUNK_ELEMS) + (cb4 & 1) * 16384;

    vfloat4 acc[2][8];
#pragma unroll
    for (int a = 0; a < 2; ++a)
#pragma unroll
        for (int b = 0; b < 8; ++b) acc[a][b] = (vfloat4)0.0f;

    // Prologue: B DMA for dim 0 into buf0; trig(0) -> avA overlaps the DMA.
    bhalf8 a0A[2], a1A[2], a0B[2], a1B[2];
    stage_B(chunkbase, smem, 0, t);
    make_av(xp0[0] * INV2PI, k0f, k1f, &a0A[0], &a1A[0]);
    make_av(xp1[0] * INV2PI, k0f, k1f, &a0A[1], &a1A[1]);
    __syncthreads();

    for (int it2 = 0; it2 < DIMS_PER_WG; it2 += 2) {
        // Half A: consume avA on buf0; build avB(it2+1); DMA dim it2+1 -> buf1.
        {
            const int inxt = it2 + 1;              // always < DIMS_PER_WG
            stage_B(chunkbase + (size_t)inxt * 32768, smem, 1, t);
            make_av(xp0[inxt] * INV2PI, k0f, k1f, &a0B[0], &a1B[0]);
            make_av(xp1[inxt] * INV2PI, k0f, k1f, &a0B[1], &a1B[1]);
            MFMA_BLOCK(smem, a0A, a1A);
            __syncthreads();                       // buf1 DMA drained; buf0 reads done
        }
        // Half B: consume avB on buf1; build avA(it2+2); DMA dim it2+2 -> buf0.
        {
            const int inxt = it2 + 2;
            if (inxt < DIMS_PER_WG) {
                stage_B(chunkbase + (size_t)inxt * 32768, smem, 0, t);
                make_av(xp0[inxt] * INV2PI, k0f, k1f, &a0A[0], &a1A[0]);
                make_av(xp1[inxt] * INV2PI, k0f, k1f, &a0A[1], &a1A[1]);
            }
            MFMA_BLOCK(smem + B_BYTES, a0B, a1B);
            __syncthreads();                       // buf0 DMA drained; buf1 reads done
        }
    }

    // Epilogue: C/D layout col=lane&15, row=quad*4+reg (m89). KSPLIT partials via atomics.
#pragma unroll
    for (int rt = 0; rt < 2; ++rt) {
#pragma unroll
        for (int ct = 0; ct < 8; ++ct) {
            const int col  = colbase + ct * 16 + fr;
            const int row0 = rowbase + w * 32 + rt * 16 + fq * 4;
#pragma unroll
            for (int r = 0; r < 4; ++r)
                atomicAdd(out + (size_t)(row0 + r) * OUTDIM + col, acc[rt][ct][r]);
        }
    }
}

// ---------------------------------------------------------------------------
// Fallback (only if ws too small for the 32MB bf16 B): slow but correct fp32.
// ---------------------------------------------------------------------------
__global__ __launch_bounds__(256) void fkan_naive(const float* __restrict__ x,
                                                  const float* __restrict__ coeffs,
                                                  const float* __restrict__ bias,
                                                  float* __restrict__ out) {
    const int b = blockIdx.x >> 1;
    const int o = ((blockIdx.x & 1) << 8) + threadIdx.x;
    float acc = bias[o];
    const float* xrow = x + (size_t)b * INDIM;
    for (int i = 0; i < INDIM; ++i) {
        const float rv = xrow[i] * INV2PI;
        const float cd = __builtin_amdgcn_cosf(rv);
        const float sd = __builtin_amdgcn_sinf(rv);
        float c = cd, s = sd;
        const float* cp = coeffs + (size_t)i * (KKDIM * OUTDIM) + o;
#pragma unroll 4
        for (int g = 0; g < NH; ++g) {
            acc += c * cp[g * 2 * OUTDIM] + s * cp[(g * 2 + 1) * OUTDIM];
            const float nc = c * cd - s * sd;
            const float ns = s * cd + c * sd;
            c = nc; s = ns;
        }
    }
    out[(size_t)b * OUTDIM + o] = acc;
}

extern "C" void kernel_launch(void* const* d_in, const int* in_sizes, int n_in,
                              void* d_out, int out_size, void* d_ws, size_t ws_size,
                              hipStream_t stream) {
    (void)in_sizes; (void)n_in; (void)out_size;
    const float* x      = (const float*)d_in[0];
    const float* coeffs = (const float*)d_in[1];
    const float* bias   = (const float*)d_in[2];
    float* out          = (float*)d_out;

    const size_t bt_bytes = (size_t)2 * INDIM * CHUNK_ELEMS * sizeof(unsigned short); // 32 MiB
    if (ws_size >= bt_bytes) {
        unsigned short* Bt = (unsigned short*)d_ws;
        fkan_prepass<<<2 * INDIM, 256, 0, stream>>>(coeffs, Bt);          // 1024 blocks
        fkan_bias_init<<<(BATCH * OUTDIM) / (4 * 256), 256, 0, stream>>>(bias, out);
        fkan_main<<<(BATCH / BM) * (OUTDIM / BN) * KSPLIT, THREADS, 0, stream>>>(x, Bt, out);
    } else {
        fkan_naive<<<BATCH * 2, 256, 0, stream>>>(x, coeffs, bias, out);
    }
}